// Round 4
// baseline (2192.594 us; speedup 1.0000x reference)
//
#include <hip/hip_runtime.h>

#define T_LEN 4096

typedef float v2f __attribute__((ext_vector_type(2)));

__device__ __forceinline__ float frcp(float x) { return __builtin_amdgcn_rcpf(x); }
__device__ __forceinline__ float fexp2(float x) { return __builtin_amdgcn_exp2f(x); }

__device__ __forceinline__ float rl(float v, int lane) {
  // wave-uniform read of lane's value -> SGPR (usable as scalar VALU operand)
  return __int_as_float(__builtin_amdgcn_readlane(__float_as_int(v), lane));
}
__device__ __forceinline__ float rfl(float v) {
  return __int_as_float(__builtin_amdgcn_readfirstlane(__float_as_int(v)));
}

// packed dual-FMA: acc = w*s + acc (VOP3P, full-rate fp32 pairs).
// s is a wave-uniform SGPR pair (the single allowed scalar operand).
__device__ __forceinline__ void pk_fma_s(v2f& acc, v2f w, v2f s) {
  asm("v_pk_fma_f32 %0, %1, %2, %0" : "+v"(acc) : "v"(w), "s"(s));
}

// quad_perm DPP butterfly adds: xor1 = 0xB1, xor2 = 0x4E
template <int CTRL>
__device__ __forceinline__ float dpp_add(float x) {
  int t = __builtin_amdgcn_mov_dpp(__float_as_int(x), CTRL, 0xF, 0xF, true);
  return x + __int_as_float(t);
}

// tanh(x) = 1 - 2/(1+exp2(x')), x' pre-scaled by 2*log2e (robust at +-inf)
__device__ __forceinline__ float tanh_pre(float x) {
  return fmaf(-2.0f, frcp(1.0f + fexp2(x)), 1.0f);
}

// TWO batch chains per wave (grid = 256). Weights shared across chains; the
// two chains' independent dependency chains interleave to fill stall slots
// (round-3 analysis: 280 cyc issue vs 715 cyc wall => 61% stalls, 1 wave/SIMD).
// Per-chain lane roles (same as round 3):
//   z-dot  : row h16 = l&15 of (p ? cW1 : vW1), p=(l>>4)&1 -> s[l&31]
//   f-dot  : row hf = l>>2 of vW2 (dup x4)
//   g-dots : rows 2l, 2l+1 of cW2 => g[hf][d0], g[hf][d0+1], d0=(2l)&7
//   reduce : quad DPP butterfly; lane keeps y[hf]; y broadcast via readlane.
__global__ __launch_bounds__(64) void disc_kernel(
    const float* __restrict__ ts, const float* __restrict__ ys,
    const float* __restrict__ iW1, const float* __restrict__ ib1,
    const float* __restrict__ iW2, const float* __restrict__ ib2,
    const float* __restrict__ vW1, const float* __restrict__ vb1,
    const float* __restrict__ vW2, const float* __restrict__ vb2,
    const float* __restrict__ cW1, const float* __restrict__ cb1,
    const float* __restrict__ cW2, const float* __restrict__ cb2,
    const float* __restrict__ rW, const float* __restrict__ rb,
    float* __restrict__ out)
{
  const int b    = blockIdx.x;          // chains 2b (A) and 2b+1 (B)
  const int l    = threadIdx.x;
  const int h16  = l & 15;
  const int p    = (l >> 4) & 1;
  const int hf   = l >> 2;
  const int d0   = (2 * l) & 7;
  const int dblk = d0 >> 1;             // 0..3 interleave block

  __shared__ __align__(16) float sbuf[32];   // init hidden [A16|B16]
  __shared__ __align__(16) float ybuf[32];   // init state  [A16|B16]
  __shared__ __align__(16) float xbuf[2048]; // 2 bufs x 64 steps x 16 floats

  const float* __restrict__ ysA = ys + (size_t)(2 * b)     * (T_LEN * 8);
  const float* __restrict__ ysB = ys + (size_t)(2 * b + 1) * (T_LEN * 8);

  const float NL2E = -1.4426950408889634f;                 // -log2(e)
  const float TSW  = 2.0f * 1.4426950408889634f * 0.909f;  // layer2 weight scale
  const float TSB  = 2.0f * 1.4426950408889634f;           // layer2 bias scale
  const float NLN2 = -0.6931471805599453f;                 // -ln 2

  // ---- per-lane weights (shared by both chains; exp2-folded scales) ----
  float w1t, b1m;
  v2f W1y2[8];
  {
    const float* W1 = p ? cW1 : vW1;
    const float* bv = p ? cb1 : vb1;
    w1t = NL2E * W1[h16 * 17];
    b1m = NL2E * bv[h16];
#pragma unroll
    for (int k = 0; k < 8; ++k) {
      v2f w; w.x = NL2E * W1[h16 * 17 + 1 + 2 * k];
             w.y = NL2E * W1[h16 * 17 + 2 + 2 * k];
      W1y2[k] = w;
    }
  }
  v2f W2p[8], G0p[8], G1p[8];
#pragma unroll
  for (int k = 0; k < 8; ++k) {
    v2f a; a.x = TSW * vW2[hf * 16 + 2 * k]; a.y = TSW * vW2[hf * 16 + 2 * k + 1];
    W2p[k] = a;
    v2f c0; c0.x = TSW * cW2[(2 * l) * 16 + 2 * k]; c0.y = TSW * cW2[(2 * l) * 16 + 2 * k + 1];
    G0p[k] = c0;
    v2f c1; c1.x = TSW * cW2[(2 * l + 1) * 16 + 2 * k]; c1.y = TSW * cW2[(2 * l + 1) * 16 + 2 * k + 1];
    G1p[k] = c1;
  }
  const float b2p  = TSB * vb2[hf];
  const float bg0p = TSB * cb2[2 * l];
  const float bg1p = TSB * cb2[2 * l + 1];

  const float t0 = ts[0];

  // ---- initial hidden states (cold path via LDS; same-wave DS is ordered) ----
  float y_ownA, y_ownB;
  v2f yuA[8], yuB[8];
  {
    float accA = ib1[h16] + iW1[h16 * 9] * t0;
    float accB = accA;
#pragma unroll
    for (int d = 0; d < 8; ++d) {
      accA = fmaf(iW1[h16 * 9 + 1 + d], ysA[d], accA);
      accB = fmaf(iW1[h16 * 9 + 1 + d], ysB[d], accB);
    }
    sbuf[h16]      = fmaxf(accA, 0.0f);
    sbuf[16 + h16] = fmaxf(accB, 0.0f);
    float y2A = ib2[h16], y2B = ib2[h16];
#pragma unroll
    for (int k = 0; k < 16; ++k) {
      y2A = fmaf(iW2[h16 * 16 + k], sbuf[k],      y2A);
      y2B = fmaf(iW2[h16 * 16 + k], sbuf[16 + k], y2B);
    }
    ybuf[h16]      = y2A;
    ybuf[16 + h16] = y2B;
    y_ownA = ybuf[hf];
    y_ownB = ybuf[16 + hf];
#pragma unroll
    for (int k = 0; k < 8; ++k) {
      v2f rA; rA.x = rfl(ybuf[2 * k]);      rA.y = rfl(ybuf[2 * k + 1]);
      v2f rB; rB.x = rfl(ybuf[16 + 2 * k]); rB.y = rfl(ybuf[16 + 2 * k + 1]);
      yuA[k] = rA; yuB[k] = rB;
    }
  }

  // ---- readout at t0 ----
  {
    float oA = rb[0], oB = rb[0];
#pragma unroll
    for (int k = 0; k < 8; ++k) {
      oA = fmaf(rW[2 * k], yuA[k].x, oA); oA = fmaf(rW[2 * k + 1], yuA[k].y, oA);
      oB = fmaf(rW[2 * k], yuB[k].x, oB); oB = fmaf(rW[2 * k + 1], yuB[k].y, oB);
    }
    if (l == 0) { out[4 * b] = oA; out[4 * b + 2] = oB; }
  }

  const int CLAMP = T_LEN * 8 - 4;

  // ---- stage chunk 0 (steps 0..63): lane l builds dx-row l for both chains,
  // interleaved per 4-float block: [A(2d),A(2d+1),B(2d),B(2d+1)] ----
  {
    const int f0 = l * 8;
    float4 a0 = *(const float4*)(ysA + f0);
    float4 a1 = *(const float4*)(ysA + f0 + 4);
    float4 a2 = *(const float4*)(ysA + f0 + 8);
    float4 a3 = *(const float4*)(ysA + f0 + 12);
    float4 b0 = *(const float4*)(ysB + f0);
    float4 b1 = *(const float4*)(ysB + f0 + 4);
    float4 b2 = *(const float4*)(ysB + f0 + 8);
    float4 b3 = *(const float4*)(ysB + f0 + 12);
    float4 dAlo, dAhi, dBlo, dBhi;
    dAlo.x = a2.x - a0.x; dAlo.y = a2.y - a0.y; dAlo.z = a2.z - a0.z; dAlo.w = a2.w - a0.w;
    dAhi.x = a3.x - a1.x; dAhi.y = a3.y - a1.y; dAhi.z = a3.z - a1.z; dAhi.w = a3.w - a1.w;
    dBlo.x = b2.x - b0.x; dBlo.y = b2.y - b0.y; dBlo.z = b2.z - b0.z; dBlo.w = b2.w - b0.w;
    dBhi.x = b3.x - b1.x; dBhi.y = b3.y - b1.y; dBhi.z = b3.z - b1.z; dBhi.w = b3.w - b1.w;
    float* w = xbuf + l * 16;
    float4 q;
    q.x = dAlo.x; q.y = dAlo.y; q.z = dBlo.x; q.w = dBlo.y; *(float4*)(w)      = q;
    q.x = dAlo.z; q.y = dAlo.w; q.z = dBlo.z; q.w = dBlo.w; *(float4*)(w + 4)  = q;
    q.x = dAhi.x; q.y = dAhi.y; q.z = dBhi.x; q.w = dBhi.y; *(float4*)(w + 8)  = q;
    q.x = dAhi.z; q.y = dAhi.w; q.z = dBhi.z; q.w = dBhi.w; *(float4*)(w + 12) = q;
  }

  float t = t0;
  for (int c = 0; c < 64; ++c) {
    // prefetch chunk c+1 rows (lane l: rows base'+l, base'+l+1, both chains)
    float4 pA0, pA1, pA2, pA3, pB0, pB1, pB2, pB3;
    {
      const int cn = min(c + 1, 63);
      const int f0 = (cn * 64 + l) * 8;
      pA0 = *(const float4*)(ysA + min(f0,      CLAMP));
      pA1 = *(const float4*)(ysA + min(f0 + 4,  CLAMP));
      pA2 = *(const float4*)(ysA + min(f0 + 8,  CLAMP));
      pA3 = *(const float4*)(ysA + min(f0 + 12, CLAMP));
      pB0 = *(const float4*)(ysB + min(f0,      CLAMP));
      pB1 = *(const float4*)(ysB + min(f0 + 4,  CLAMP));
      pB2 = *(const float4*)(ysB + min(f0 + 8,  CLAMP));
      pB3 = *(const float4*)(ysB + min(f0 + 12, CLAMP));
    }
    const float* __restrict__ xb = xbuf + (c & 1) * 1024;
    const int base = c * 64;
    const int nsteps = min(64, (T_LEN - 1) - base);
    for (int j = 0; j < nsteps; ++j) {
      // one ds_read_b128 serves both chains: (dxA[d0],dxA[d0+1],dxB[d0],dxB[d0+1])
      const float4 dx4 = *(const float4*)(xb + j * 16 + 4 * dblk);

      // ---- z-dots, both chains (SGPR yu as scalar pk operand) ----
      const float mt = fmaf(w1t, t, b1m);
      v2f maA; maA.x = mt; maA.y = 0.0f;  v2f mbA; mbA.x = 0.0f; mbA.y = 0.0f;
      v2f maB; maB.x = mt; maB.y = 0.0f;  v2f mbB; mbB.x = 0.0f; mbB.y = 0.0f;
#pragma unroll
      for (int k = 0; k < 4; ++k) {
        pk_fma_s(maA, W1y2[k],     yuA[k]);
        pk_fma_s(maB, W1y2[k],     yuB[k]);
        pk_fma_s(mbA, W1y2[4 + k], yuA[4 + k]);
        pk_fma_s(mbB, W1y2[4 + k], yuB[4 + k]);
      }
      const v2f msA = maA + mbA;  const float mA = msA.x + msA.y;
      const v2f msB = maB + mbB;  const float mB = msB.x + msB.y;

      // ---- silu both chains (per-lane, no duplication cost) ----
      const float eA = fexp2(mA);
      const float eB = fexp2(mB);
      const float sA = (mA * NLN2) * frcp(1.0f + eA);
      const float sB = (mB * NLN2) * frcp(1.0f + eB);

      // ---- g-dots (readlanes consumed in-loop to cap live SGPRs) ----
      v2f gaA; gaA.x = bg0p; gaA.y = 0.0f;  v2f gcA; gcA.x = 0.0f; gcA.y = 0.0f;
      v2f gbA; gbA.x = bg1p; gbA.y = 0.0f;  v2f gdA; gdA.x = 0.0f; gdA.y = 0.0f;
      v2f gaB; gaB.x = bg0p; gaB.y = 0.0f;  v2f gcB; gcB.x = 0.0f; gcB.y = 0.0f;
      v2f gbB; gbB.x = bg1p; gbB.y = 0.0f;  v2f gdB; gdB.x = 0.0f; gdB.y = 0.0f;
#pragma unroll
      for (int k = 0; k < 4; ++k) {
        v2f slA; slA.x = rl(sA, 16 + 2 * k); slA.y = rl(sA, 17 + 2 * k);
        v2f shA; shA.x = rl(sA, 24 + 2 * k); shA.y = rl(sA, 25 + 2 * k);
        v2f slB; slB.x = rl(sB, 16 + 2 * k); slB.y = rl(sB, 17 + 2 * k);
        v2f shB; shB.x = rl(sB, 24 + 2 * k); shB.y = rl(sB, 25 + 2 * k);
        pk_fma_s(gaA, G0p[k], slA);  pk_fma_s(gcA, G0p[4 + k], shA);
        pk_fma_s(gbA, G1p[k], slA);  pk_fma_s(gdA, G1p[4 + k], shA);
        pk_fma_s(gaB, G0p[k], slB);  pk_fma_s(gcB, G0p[4 + k], shB);
        pk_fma_s(gbB, G1p[k], slB);  pk_fma_s(gdB, G1p[4 + k], shB);
      }

      // ---- f-dots ----
      v2f faA; faA.x = b2p; faA.y = 0.0f;  v2f fbA; fbA.x = 0.0f; fbA.y = 0.0f;
      v2f faB; faB.x = b2p; faB.y = 0.0f;  v2f fbB; fbB.x = 0.0f; fbB.y = 0.0f;
#pragma unroll
      for (int k = 0; k < 4; ++k) {
        v2f slA; slA.x = rl(sA, 2 * k);     slA.y = rl(sA, 2 * k + 1);
        v2f shA; shA.x = rl(sA, 8 + 2 * k); shA.y = rl(sA, 9 + 2 * k);
        v2f slB; slB.x = rl(sB, 2 * k);     slB.y = rl(sB, 2 * k + 1);
        v2f shB; shB.x = rl(sB, 8 + 2 * k); shB.y = rl(sB, 9 + 2 * k);
        pk_fma_s(faA, W2p[k], slA);  pk_fma_s(fbA, W2p[4 + k], shA);
        pk_fma_s(faB, W2p[k], slB);  pk_fma_s(fbB, W2p[4 + k], shB);
      }

      // ---- tanhs ----
      const v2f gsA0 = gaA + gcA;  const v2f gsA1 = gbA + gdA;
      const v2f gsB0 = gaB + gcB;  const v2f gsB1 = gbB + gdB;
      const float g0A = tanh_pre(gsA0.x + gsA0.y);
      const float g1A = tanh_pre(gsA1.x + gsA1.y);
      const float g0B = tanh_pre(gsB0.x + gsB0.y);
      const float g1B = tanh_pre(gsB1.x + gsB1.y);
      const v2f fsA = faA + fbA;   const v2f fsB = faB + fbB;
      const float fvA = tanh_pre(fsA.x + fsA.y);
      const float fvB = tanh_pre(fsB.x + fsB.y);

      // ---- einsum partials + quad butterfly reduce ----
      float prA = fmaf(g0A, dx4.x, g1A * dx4.y);
      float prB = fmaf(g0B, dx4.z, g1B * dx4.w);
      prA = dpp_add<0xB1>(prA);  prA = dpp_add<0x4E>(prA);
      prB = dpp_add<0xB1>(prB);  prB = dpp_add<0x4E>(prB);

      y_ownA = y_ownA + (fvA + prA);
      y_ownB = y_ownB + (fvB + prB);
#pragma unroll
      for (int k = 0; k < 8; ++k) {
        v2f rA; rA.x = rl(y_ownA, 8 * k); rA.y = rl(y_ownA, 8 * k + 4);
        yuA[k] = rA;
        v2f rB; rB.x = rl(y_ownB, 8 * k); rB.y = rl(y_ownB, 8 * k + 4);
        yuB[k] = rB;
      }
      t += 1.0f;
    }
    // write prefetched chunk into the other buffer
    {
      float* w = xbuf + ((c + 1) & 1) * 1024 + l * 16;
      float4 q;
      q.x = pA2.x - pA0.x; q.y = pA2.y - pA0.y; q.z = pB2.x - pB0.x; q.w = pB2.y - pB0.y;
      *(float4*)(w) = q;
      q.x = pA2.z - pA0.z; q.y = pA2.w - pA0.w; q.z = pB2.z - pB0.z; q.w = pB2.w - pB0.w;
      *(float4*)(w + 4) = q;
      q.x = pA3.x - pA1.x; q.y = pA3.y - pA1.y; q.z = pB3.x - pB1.x; q.w = pB3.y - pB1.y;
      *(float4*)(w + 8) = q;
      q.x = pA3.z - pA1.z; q.y = pA3.w - pA1.w; q.z = pB3.z - pB1.z; q.w = pB3.w - pB1.w;
      *(float4*)(w + 12) = q;
    }
  }

  // ---- readout at t1 ----
  {
    float oA = rb[0], oB = rb[0];
#pragma unroll
    for (int k = 0; k < 8; ++k) {
      oA = fmaf(rW[2 * k], yuA[k].x, oA); oA = fmaf(rW[2 * k + 1], yuA[k].y, oA);
      oB = fmaf(rW[2 * k], yuB[k].x, oB); oB = fmaf(rW[2 * k + 1], yuB[k].y, oB);
    }
    if (l == 0) { out[4 * b + 1] = oA; out[4 * b + 3] = oB; }
  }
}

extern "C" void kernel_launch(void* const* d_in, const int* in_sizes, int n_in,
                              void* d_out, int out_size, void* d_ws, size_t ws_size,
                              hipStream_t stream) {
  (void)in_sizes; (void)n_in; (void)out_size; (void)d_ws; (void)ws_size;
  const float* ts  = (const float*)d_in[0];
  const float* ys  = (const float*)d_in[1];
  const float* iW1 = (const float*)d_in[2];
  const float* ib1 = (const float*)d_in[3];
  const float* iW2 = (const float*)d_in[4];
  const float* ib2 = (const float*)d_in[5];
  const float* vW1 = (const float*)d_in[6];
  const float* vb1 = (const float*)d_in[7];
  const float* vW2 = (const float*)d_in[8];
  const float* vb2 = (const float*)d_in[9];
  const float* cW1 = (const float*)d_in[10];
  const float* cb1 = (const float*)d_in[11];
  const float* cW2 = (const float*)d_in[12];
  const float* cb2 = (const float*)d_in[13];
  const float* rW  = (const float*)d_in[14];
  const float* rb  = (const float*)d_in[15];
  float* out = (float*)d_out;
  hipLaunchKernelGGL(disc_kernel, dim3(256), dim3(64), 0, stream,
                     ts, ys, iW1, ib1, iW2, ib2, vW1, vb1, vW2, vb2,
                     cW1, cb1, cW2, cb2, rW, rb, out);
}

// Round 5
// 1629.811 us; speedup vs baseline: 1.3453x; 1.3453x over previous
//
#include <hip/hip_runtime.h>

#define T_LEN 4096

typedef float v2f __attribute__((ext_vector_type(2)));

__device__ __forceinline__ float frcp(float x)  { return __builtin_amdgcn_rcpf(x); }
__device__ __forceinline__ float fexp2(float x) { return __builtin_amdgcn_exp2f(x); }

// VGPR->VGPR cross-lane via DPP (VALU pipe; no SGPR hazards)
template <int CTRL>
__device__ __forceinline__ float mdpp(float x) {
  return __int_as_float(__builtin_amdgcn_mov_dpp(__float_as_int(x), CTRL, 0xF, 0xF, true));
}
template <int CTRL>
__device__ __forceinline__ float dpp_add(float x) {  // x + dpp(x)
  return x + mdpp<CTRL>(x);
}
// quad_perm rotates: dst lane k <- lane (k+1)&3 : [1,2,3,0] = 0x39
//                    (k+2)&3 : [2,3,0,1] = 0x4E ; (k+3)&3 : [3,0,1,2] = 0x93
// row_ror:4 = 0x124, row_ror:8 = 0x128 (reduce over stride-4 lanes in 16-row)

template <int PATT>
__device__ __forceinline__ float swz(float x) {
  return __int_as_float(__builtin_amdgcn_ds_swizzle(__float_as_int(x), PATT));
}
__device__ __forceinline__ float bperm(int idx_bytes, float x) {
  return __int_as_float(__builtin_amdgcn_ds_bpermute(idx_bytes, __float_as_int(x)));
}
__device__ __forceinline__ void pk_fma(v2f& acc, v2f w, v2f s) {
  asm("v_pk_fma_f32 %0, %1, %2, %0" : "+v"(acc) : "v"(w), "v"(s));
}
// tanh(x) = 1 - 2/(1+exp2(X)), X pre-scaled by 2*log2e (robust at +-inf)
__device__ __forceinline__ float tanh_pre(float X) {
  return fmaf(-2.0f, frcp(1.0f + fexp2(X)), 1.0f);
}

// One wave per batch element. Distributed-matvec dataflow, ZERO readlanes:
//  lane l: b=l&3, a=(l>>2)&3, r=l>>4; h=b+4r (y/g/f row), j=b+4a (L1 row/s idx)
//  y[h] on lane; quad holds y[4r..4r+3] -> 3 quad_perm gather
//  L1: rows j of vW1,cW1 x cols [4r,4r+4); reduce over r: swizzle xor16 + bpermute xor32
//  s[j] on lane; quad holds s[4a..4a+3] -> 6 quad_perm gather (sv,sc)
//  g: rows [8h,8h+8) x cols [4a,4a+4); reduce over a: row_ror:4/8 DPP adds
//  f: row h x cols [4a,4a+4); same reduce
//  einsum: in-lane over d (dx broadcast from LDS), no reduce; y[h] += tanh(f)+e
__global__ __launch_bounds__(64) void disc_kernel(
    const float* __restrict__ ts, const float* __restrict__ ys,
    const float* __restrict__ iW1, const float* __restrict__ ib1,
    const float* __restrict__ iW2, const float* __restrict__ ib2,
    const float* __restrict__ vW1, const float* __restrict__ vb1,
    const float* __restrict__ vW2, const float* __restrict__ vb2,
    const float* __restrict__ cW1, const float* __restrict__ cb1,
    const float* __restrict__ cW2, const float* __restrict__ cb2,
    const float* __restrict__ rW, const float* __restrict__ rb,
    float* __restrict__ out)
{
  const int blk = blockIdx.x;
  const int l   = threadIdx.x;
  const int bq  = l & 3;
  const int aq  = (l >> 2) & 3;
  const int rq  = l >> 4;
  const int hL  = bq + 4 * rq;   // y/g/f row owned by this lane
  const int jL  = bq + 4 * aq;   // L1 row / s index owned by this lane

  __shared__ float yb[16];
  __shared__ __align__(16) float xbuf[2 * 512];  // 2 bufs x 64 dx rows x 8

  const float* __restrict__ ysb = ys + (size_t)blk * (T_LEN * 8);

  const float NL2E = -1.4426950408889634f;                 // -log2(e)
  const float TSW  = 2.0f * 1.4426950408889634f * 0.909f;  // L2 weight scale
  const float TSB  = 2.0f * 1.4426950408889634f;           // L2 bias scale
  const float NLN2 = -0.6931471805599453f;                 // -ln 2

  // column orders (rotated per-lane to match quad_perm gather order)
  const int c1[4] = { ((bq + 0) & 3) + 4 * rq, ((bq + 1) & 3) + 4 * rq,
                      ((bq + 2) & 3) + 4 * rq, ((bq + 3) & 3) + 4 * rq };
  const int c2[4] = { ((bq + 0) & 3) + 4 * aq, ((bq + 1) & 3) + 4 * aq,
                      ((bq + 2) & 3) + 4 * aq, ((bq + 3) & 3) + 4 * aq };

  // ---- L1 weights: rows jL of vW1/cW1, cols c1[0..3], scaled by -log2e ----
  v2f WV0, WV1, WC0, WC1;
  WV0.x = NL2E * vW1[jL * 17 + 1 + c1[0]]; WV0.y = NL2E * vW1[jL * 17 + 1 + c1[1]];
  WV1.x = NL2E * vW1[jL * 17 + 1 + c1[2]]; WV1.y = NL2E * vW1[jL * 17 + 1 + c1[3]];
  WC0.x = NL2E * cW1[jL * 17 + 1 + c1[0]]; WC0.y = NL2E * cW1[jL * 17 + 1 + c1[1]];
  WC1.x = NL2E * cW1[jL * 17 + 1 + c1[2]]; WC1.y = NL2E * cW1[jL * 17 + 1 + c1[3]];
  // t-term + bias contribute once per reduce-group (r==0 lanes only)
  const float w1tv = (rq == 0) ? NL2E * vW1[jL * 17] : 0.0f;
  const float b1v  = (rq == 0) ? NL2E * vb1[jL]      : 0.0f;
  const float w1tc = (rq == 0) ? NL2E * cW1[jL * 17] : 0.0f;
  const float b1c  = (rq == 0) ? NL2E * cb1[jL]      : 0.0f;

  // ---- L2 f: row hL, cols c2[0..3] ----
  v2f FW0, FW1;
  FW0.x = TSW * vW2[hL * 16 + c2[0]]; FW0.y = TSW * vW2[hL * 16 + c2[1]];
  FW1.x = TSW * vW2[hL * 16 + c2[2]]; FW1.y = TSW * vW2[hL * 16 + c2[3]];
  const float fb = (aq == 0) ? TSB * vb2[hL] : 0.0f;

  // ---- L2 g: rows 8hL+d, cols c2[0..3] ----
  v2f GW0[8], GW1[8];
  float gbi[8];
#pragma unroll
  for (int d = 0; d < 8; ++d) {
    const int row = 8 * hL + d;
    GW0[d].x = TSW * cW2[row * 16 + c2[0]]; GW0[d].y = TSW * cW2[row * 16 + c2[1]];
    GW1[d].x = TSW * cW2[row * 16 + c2[2]]; GW1[d].y = TSW * cW2[row * 16 + c2[3]];
    gbi[d] = (aq == 0) ? TSB * cb2[row] : 0.0f;
  }

  const int idx32 = ((l ^ 32) << 2);   // bpermute byte index for xor-32
  const float t0 = ts[0];

  // ---- init y0 = iMLP([t0, x0]) (cold; same-wave LDS is ordered) ----
  float y_own;
  {
    __shared__ float sb[16];
    float hid = ib1[l & 15] + iW1[(l & 15) * 9] * t0;
#pragma unroll
    for (int d = 0; d < 8; ++d) hid = fmaf(iW1[(l & 15) * 9 + 1 + d], ysb[d], hid);
    sb[l & 15] = fmaxf(hid, 0.0f);
    float y0 = ib2[hL];
#pragma unroll
    for (int k = 0; k < 16; ++k) y0 = fmaf(iW2[hL * 16 + k], sb[k], y0);
    y_own = y0;
  }
  // readout t0
  yb[hL] = y_own;
  if (l == 0) {
    float o = rb[0];
#pragma unroll
    for (int k = 0; k < 16; ++k) o = fmaf(rW[k], yb[k], o);
    out[2 * blk] = o;
  }

  // ---- stage dx chunk 0: lane l -> dx row l ----
  {
    const int row = min(l, T_LEN - 2);
    const float4 x0a = *(const float4*)(ysb + row * 8);
    const float4 x0b = *(const float4*)(ysb + row * 8 + 4);
    const float4 x1a = *(const float4*)(ysb + row * 8 + 8);
    const float4 x1b = *(const float4*)(ysb + row * 8 + 12);
    float4 e0, e1;
    e0.x = x1a.x - x0a.x; e0.y = x1a.y - x0a.y; e0.z = x1a.z - x0a.z; e0.w = x1a.w - x0a.w;
    e1.x = x1b.x - x0b.x; e1.y = x1b.y - x0b.y; e1.z = x1b.z - x0b.z; e1.w = x1b.w - x0b.w;
    *(float4*)(xbuf + l * 8)     = e0;
    *(float4*)(xbuf + l * 8 + 4) = e1;
  }

  float t = t0;
  for (int c = 0; c < 64; ++c) {
    // prefetch next chunk's rows into registers
    float4 p0a, p0b, p1a, p1b;
    {
      const int row = min((c + 1) * 64 + l, T_LEN - 2);
      p0a = *(const float4*)(ysb + row * 8);
      p0b = *(const float4*)(ysb + row * 8 + 4);
      p1a = *(const float4*)(ysb + row * 8 + 8);
      p1b = *(const float4*)(ysb + row * 8 + 12);
    }
    const float* __restrict__ xb = xbuf + (c & 1) * 512;
    const int nsteps = min(64, (T_LEN - 1) - c * 64);
    for (int j = 0; j < nsteps; ++j) {
      // dx broadcast (same addr all lanes); latency hidden under L1
      const float4 dxq0 = *(const float4*)(xb + j * 8);
      const float4 dxq1 = *(const float4*)(xb + j * 8 + 4);

      // ---- y gather (3 quad_perm) ----
      const float yv1 = mdpp<0x39>(y_own);
      const float yv2 = mdpp<0x4E>(y_own);
      const float yv3 = mdpp<0x93>(y_own);
      v2f yp0; yp0.x = y_own; yp0.y = yv1;
      v2f yp1; yp1.x = yv2;   yp1.y = yv3;

      // ---- L1 partials ----
      v2f uv; uv.x = fmaf(w1tv, t, b1v); uv.y = 0.0f;
      v2f uc; uc.x = fmaf(w1tc, t, b1c); uc.y = 0.0f;
      pk_fma(uv, WV0, yp0); pk_fma(uv, WV1, yp1);
      pk_fma(uc, WC0, yp0); pk_fma(uc, WC1, yp1);
      float uvs = uv.x + uv.y;
      float ucs = uc.x + uc.y;

      // ---- reduce over r: xor16 (swizzle) then xor32 (bpermute) ----
      uvs += swz<0x401F>(uvs);
      ucs += swz<0x401F>(ucs);
      uvs += bperm(idx32, uvs);
      ucs += bperm(idx32, ucs);

      // ---- silu (exp2-folded): s = u * sigmoid(u), u = m * -ln2 ----
      const float sv = (uvs * NLN2) * frcp(1.0f + fexp2(uvs));
      const float sc = (ucs * NLN2) * frcp(1.0f + fexp2(ucs));

      // ---- s gather (6 quad_perm) ----
      const float sv1 = mdpp<0x39>(sv), sv2 = mdpp<0x4E>(sv), sv3 = mdpp<0x93>(sv);
      const float sc1 = mdpp<0x39>(sc), sc2 = mdpp<0x4E>(sc), sc3 = mdpp<0x93>(sc);
      v2f svp0; svp0.x = sv;  svp0.y = sv1;
      v2f svp1; svp1.x = sv2; svp1.y = sv3;
      v2f scp0; scp0.x = sc;  scp0.y = sc1;
      v2f scp1; scp1.x = sc2; scp1.y = sc3;

      // ---- g partials (8 rows x 4 cols) ----
      float gs[8];
#pragma unroll
      for (int d = 0; d < 8; ++d) {
        v2f ga; ga.x = gbi[d]; ga.y = 0.0f;
        pk_fma(ga, GW0[d], scp0);
        pk_fma(ga, GW1[d], scp1);
        gs[d] = ga.x + ga.y;
      }
      // ---- f partial ----
      v2f fa; fa.x = fb; fa.y = 0.0f;
      pk_fma(fa, FW0, svp0); pk_fma(fa, FW1, svp1);
      float fs = fa.x + fa.y;

      // ---- reduce over a: row_ror:4 then row_ror:8 (VALU DPP adds) ----
#pragma unroll
      for (int d = 0; d < 8; ++d) gs[d] = dpp_add<0x124>(gs[d]);
      fs = dpp_add<0x124>(fs);
#pragma unroll
      for (int d = 0; d < 8; ++d) gs[d] = dpp_add<0x128>(gs[d]);
      fs = dpp_add<0x128>(fs);

      // ---- tanh + in-lane einsum over d ----
      const float fv = tanh_pre(fs);
      float e0 = tanh_pre(gs[0]) * dxq0.x;
      float e1 = tanh_pre(gs[1]) * dxq0.y;
      e0 = fmaf(tanh_pre(gs[2]), dxq0.z, e0);
      e1 = fmaf(tanh_pre(gs[3]), dxq0.w, e1);
      e0 = fmaf(tanh_pre(gs[4]), dxq1.x, e0);
      e1 = fmaf(tanh_pre(gs[5]), dxq1.y, e1);
      e0 = fmaf(tanh_pre(gs[6]), dxq1.z, e0);
      e1 = fmaf(tanh_pre(gs[7]), dxq1.w, e1);

      y_own = y_own + (fv + (e0 + e1));
      t += 1.0f;
    }
    // write prefetched dx rows into the other buffer
    {
      float4 e0, e1;
      e0.x = p1a.x - p0a.x; e0.y = p1a.y - p0a.y; e0.z = p1a.z - p0a.z; e0.w = p1a.w - p0a.w;
      e1.x = p1b.x - p0b.x; e1.y = p1b.y - p0b.y; e1.z = p1b.z - p0b.z; e1.w = p1b.w - p0b.w;
      float* xw = xbuf + ((c + 1) & 1) * 512;
      *(float4*)(xw + l * 8)     = e0;
      *(float4*)(xw + l * 8 + 4) = e1;
    }
  }

  // ---- readout t1 ----
  yb[hL] = y_own;
  if (l == 0) {
    float o = rb[0];
#pragma unroll
    for (int k = 0; k < 16; ++k) o = fmaf(rW[k], yb[k], o);
    out[2 * blk + 1] = o;
  }
}

extern "C" void kernel_launch(void* const* d_in, const int* in_sizes, int n_in,
                              void* d_out, int out_size, void* d_ws, size_t ws_size,
                              hipStream_t stream) {
  (void)in_sizes; (void)n_in; (void)out_size; (void)d_ws; (void)ws_size;
  const float* ts  = (const float*)d_in[0];
  const float* ys  = (const float*)d_in[1];
  const float* iW1 = (const float*)d_in[2];
  const float* ib1 = (const float*)d_in[3];
  const float* iW2 = (const float*)d_in[4];
  const float* ib2 = (const float*)d_in[5];
  const float* vW1 = (const float*)d_in[6];
  const float* vb1 = (const float*)d_in[7];
  const float* vW2 = (const float*)d_in[8];
  const float* vb2 = (const float*)d_in[9];
  const float* cW1 = (const float*)d_in[10];
  const float* cb1 = (const float*)d_in[11];
  const float* cW2 = (const float*)d_in[12];
  const float* cb2 = (const float*)d_in[13];
  const float* rW  = (const float*)d_in[14];
  const float* rb  = (const float*)d_in[15];
  float* out = (float*)d_out;
  hipLaunchKernelGGL(disc_kernel, dim3(512), dim3(64), 0, stream,
                     ts, ys, iW1, ib1, iW2, ib2, vW1, vb1, vW2, vb2,
                     cW1, cb1, cW2, cb2, rW, rb, out);
}

// Round 6
// 1610.503 us; speedup vs baseline: 1.3614x; 1.0120x over previous
//
#include <hip/hip_runtime.h>

#define T_LEN 4096

typedef float v2f __attribute__((ext_vector_type(2)));

__device__ __forceinline__ float frcp(float x)  { return __builtin_amdgcn_rcpf(x); }
__device__ __forceinline__ float fexp2(float x) { return __builtin_amdgcn_exp2f(x); }

template <int CTRL>
__device__ __forceinline__ float mdpp(float x) {
  return __int_as_float(__builtin_amdgcn_mov_dpp(__float_as_int(x), CTRL, 0xF, 0xF, true));
}
// lane <- lane^16 within each 32-lane group (BitMode: xor=0x10,and=0x1F)
__device__ __forceinline__ float swz16(float x) {
  return __int_as_float(__builtin_amdgcn_ds_swizzle(__float_as_int(x), 0x401F));
}
__device__ __forceinline__ void pk_fma(v2f& acc, v2f w, v2f s) {
  asm("v_pk_fma_f32 %0, %1, %2, %0" : "+v"(acc) : "v"(w), "v"(s));
}
// tanh(a) where X = 2*log2e*a  (robust at +-inf)
__device__ __forceinline__ float tanh_pre(float X) {
  return fmaf(-2.0f, frcp(1.0f + fexp2(X)), 1.0f);
}

// Row-gather: P[m] = ( v[(j-m)&15], v[(j-m+8)&15] ) via row_ror:m / row_ror:m+8.
// 15 independent DPP movs, all sourced from `own` (depth 1).
#define GATHER16(P, own)                                              \
  P[0].x = (own);            P[0].y = mdpp<0x128>(own);               \
  P[1].x = mdpp<0x121>(own); P[1].y = mdpp<0x129>(own);               \
  P[2].x = mdpp<0x122>(own); P[2].y = mdpp<0x12A>(own);               \
  P[3].x = mdpp<0x123>(own); P[3].y = mdpp<0x12B>(own);               \
  P[4].x = mdpp<0x124>(own); P[4].y = mdpp<0x12C>(own);               \
  P[5].x = mdpp<0x125>(own); P[5].y = mdpp<0x12D>(own);               \
  P[6].x = mdpp<0x126>(own); P[6].y = mdpp<0x12E>(own);               \
  P[7].x = mdpp<0x127>(own); P[7].y = mdpp<0x12F>(own);

__device__ __forceinline__ float dot16(const v2f* __restrict__ W,
                                       const v2f* __restrict__ P, float seed) {
  v2f a0; a0.x = seed; a0.y = 0.0f;
  v2f a1; a1.x = 0.0f; a1.y = 0.0f;
  pk_fma(a0, W[0], P[0]); pk_fma(a1, W[1], P[1]);
  pk_fma(a0, W[2], P[2]); pk_fma(a1, W[3], P[3]);
  pk_fma(a0, W[4], P[4]); pk_fma(a1, W[5], P[5]);
  pk_fma(a0, W[6], P[6]); pk_fma(a1, W[7], P[7]);
  const v2f s = a0 + a1;
  return s.x + s.y;
}

// TWO chains per wave (lane halves), 32 lanes per chain, 256 blocks x 64 thr.
// Within a half: j = l&15 (row position), u = (l>>4)&1 (row).
//  y distributed: lane (j,u) holds y[j] (row-duplicated).
//  L1: lane computes s1[j] AND s2[j] in-lane over row_ror-gathered y (row-dup).
//  L2 g: lane owns rows j*8 + 4u + i (i=0..3) of cW2 -> d-half split by row.
//  L2 f: f[j] row-duplicated.
//  e-reduce over rows: ONE ds_swizzle xor16; f-work scheduled under it.
__global__ __launch_bounds__(64) void disc_kernel(
    const float* __restrict__ ts, const float* __restrict__ ys,
    const float* __restrict__ iW1, const float* __restrict__ ib1,
    const float* __restrict__ iW2, const float* __restrict__ ib2,
    const float* __restrict__ vW1, const float* __restrict__ vb1,
    const float* __restrict__ vW2, const float* __restrict__ vb2,
    const float* __restrict__ cW1, const float* __restrict__ cb1,
    const float* __restrict__ cW2, const float* __restrict__ cb2,
    const float* __restrict__ rW, const float* __restrict__ rb,
    float* __restrict__ out)
{
  const int blk = blockIdx.x;
  const int l   = threadIdx.x;
  const int j   = l & 15;
  const int u   = (l >> 4) & 1;
  const int hf2 = l >> 5;
  const int q   = l & 31;
  const int ch  = 2 * blk + hf2;            // chain (batch) index

  __shared__ float sbuf[32];                 // init hidden, per half
  __shared__ float ybq[32];                  // readout staging, per half
  __shared__ __align__(16) float xbuf[2048]; // 2 bufs x 2 chains x 64 x 8

  const float* __restrict__ ysc = ys + (size_t)ch * (T_LEN * 8);

  const float NL2E = -1.4426950408889634f;                 // -log2(e)
  const float TSW  = 2.0f * 1.4426950408889634f * 0.909f;  // L2 weight scale
  const float TSB  = 2.0f * 1.4426950408889634f;           // L2 bias scale
  const float NLN2 = -0.6931471805599453f;                 // -ln 2

  // slot->column maps for row_ror gathers
  int idxm[8], idx8[8];
#pragma unroll
  for (int m = 0; m < 8; ++m) { idxm[m] = (j - m) & 15; idx8[m] = (idxm[m] + 8) & 15; }

  // ---- L1 weights: rows j of vW1/cW1, slot-permuted, scaled by -log2e ----
  v2f WVp[8], WCp[8];
#pragma unroll
  for (int m = 0; m < 8; ++m) {
    WVp[m].x = NL2E * vW1[j * 17 + 1 + idxm[m]];
    WVp[m].y = NL2E * vW1[j * 17 + 1 + idx8[m]];
    WCp[m].x = NL2E * cW1[j * 17 + 1 + idxm[m]];
    WCp[m].y = NL2E * cW1[j * 17 + 1 + idx8[m]];
  }
  const float wv_t = NL2E * vW1[j * 17];
  const float bv   = NL2E * vb1[j];
  const float wc_t = NL2E * cW1[j * 17];
  const float bc   = NL2E * cb1[j];

  // ---- L2 f: row j of vW2, slot-permuted ----
  v2f FWp[8];
#pragma unroll
  for (int m = 0; m < 8; ++m) {
    FWp[m].x = TSW * vW2[j * 16 + idxm[m]];
    FWp[m].y = TSW * vW2[j * 16 + idx8[m]];
  }
  const float fbv = TSB * vb2[j];

  // ---- L2 g: rows j*8 + 4u + i of cW2, slot-permuted ----
  v2f GW[4][8];
  float gb[4];
#pragma unroll
  for (int i = 0; i < 4; ++i) {
    const int r = j * 8 + 4 * u + i;
#pragma unroll
    for (int m = 0; m < 8; ++m) {
      GW[i][m].x = TSW * cW2[r * 16 + idxm[m]];
      GW[i][m].y = TSW * cW2[r * 16 + idx8[m]];
    }
    gb[i] = TSB * cb2[r];
  }

  const float t0 = ts[0];

  // ---- init: y0 = iMLP([t0, x0]); distributed y (lane j owns y[j]) ----
  float y_own;
  {
    float hid = ib1[j] + iW1[j * 9] * t0;
#pragma unroll
    for (int d = 0; d < 8; ++d) hid = fmaf(iW1[j * 9 + 1 + d], ysc[d], hid);
    sbuf[hf2 * 16 + j] = fmaxf(hid, 0.0f);   // rows dup-write identical values
    float y0 = ib2[j];
#pragma unroll
    for (int k = 0; k < 16; ++k) y0 = fmaf(iW2[j * 16 + k], sbuf[hf2 * 16 + k], y0);
    y_own = y0;
  }
  // readout t0
  ybq[hf2 * 16 + j] = y_own;
  if (q == 0) {
    float o = rb[0];
#pragma unroll
    for (int k = 0; k < 16; ++k) o = fmaf(rW[k], ybq[hf2 * 16 + k], o);
    out[2 * ch] = o;
  }

  // ---- dx staging: lane q stages rows 2q, 2q+1 of its half's chunk ----
  const int xoff = hf2 * 512 + 4 * u;       // per-step read offset base
  {
    const int r0 = 2 * q;
    const int ra = min(r0,     T_LEN - 1), rb_ = min(r0 + 1, T_LEN - 1),
              rc = min(r0 + 2, T_LEN - 1);
    const float4 a0 = *(const float4*)(ysc + ra * 8);
    const float4 a1 = *(const float4*)(ysc + ra * 8 + 4);
    const float4 b0 = *(const float4*)(ysc + rb_ * 8);
    const float4 b1 = *(const float4*)(ysc + rb_ * 8 + 4);
    const float4 c0 = *(const float4*)(ysc + rc * 8);
    const float4 c1 = *(const float4*)(ysc + rc * 8 + 4);
    float* w = xbuf + hf2 * 512 + 16 * q;
    float4 d0, d1;
    d0.x = b0.x - a0.x; d0.y = b0.y - a0.y; d0.z = b0.z - a0.z; d0.w = b0.w - a0.w;
    d1.x = b1.x - a1.x; d1.y = b1.y - a1.y; d1.z = b1.z - a1.z; d1.w = b1.w - a1.w;
    *(float4*)(w)     = d0;  *(float4*)(w + 4)  = d1;
    d0.x = c0.x - b0.x; d0.y = c0.y - b0.y; d0.z = c0.z - b0.z; d0.w = c0.w - b0.w;
    d1.x = c1.x - b1.x; d1.y = c1.y - b1.y; d1.z = c1.z - b1.z; d1.w = c1.w - b1.w;
    *(float4*)(w + 8) = d0;  *(float4*)(w + 12) = d1;
  }

  float t = t0;
  for (int c = 0; c < 64; ++c) {
    // prefetch next chunk's rows into registers (clamped)
    float4 pa0, pa1, pb0, pb1, pc0, pc1;
    {
      const int r0 = (c + 1 < 64 ? (c + 1) * 64 : c * 64) + 2 * q;
      const int ra = min(r0,     T_LEN - 1), rb_ = min(r0 + 1, T_LEN - 1),
                rc = min(r0 + 2, T_LEN - 1);
      pa0 = *(const float4*)(ysc + ra * 8);
      pa1 = *(const float4*)(ysc + ra * 8 + 4);
      pb0 = *(const float4*)(ysc + rb_ * 8);
      pb1 = *(const float4*)(ysc + rb_ * 8 + 4);
      pc0 = *(const float4*)(ysc + rc * 8);
      pc1 = *(const float4*)(ysc + rc * 8 + 4);
    }
    const float* __restrict__ xb = xbuf + (c & 1) * 1024 + xoff;
    const int nsteps = min(64, (T_LEN - 1) - c * 64);
    for (int js = 0; js < nsteps; ++js) {
      // this lane's 4 dx components (d = 4u..4u+3); read early, used late
      const float4 dx4 = *(const float4*)(xb + js * 8);

      // ---- y gather + L1 (both s on every lane; rows duplicate) ----
      v2f Py[8]; GATHER16(Py, y_own);
      const float u1 = dot16(WVp, Py, fmaf(wv_t, t, bv));
      const float u2 = dot16(WCp, Py, fmaf(wc_t, t, bc));
      // silu via exp2-folding: s = a*sigmoid(a), u* = -log2e*a
      const float s1 = (u1 * NLN2) * frcp(1.0f + fexp2(u1));
      const float s2 = (u2 * NLN2) * frcp(1.0f + fexp2(u2));

      // ---- g: 4 in-lane 16-wide dots on gathered s2, tanh, einsum part ----
      v2f Ps2[8]; GATHER16(Ps2, s2);
      const float tg0 = tanh_pre(dot16(GW[0], Ps2, gb[0]));
      const float tg1 = tanh_pre(dot16(GW[1], Ps2, gb[1]));
      const float tg2 = tanh_pre(dot16(GW[2], Ps2, gb[2]));
      const float tg3 = tanh_pre(dot16(GW[3], Ps2, gb[3]));
      const float e0 = fmaf(tg0, dx4.x, tg1 * dx4.y);
      const float e1 = fmaf(tg2, dx4.z, tg3 * dx4.w);
      const float eo = e0 + e1;
      // cross-row reduce (the ONE DS op); f-work below fills its latency
      const float eoth = swz16(eo);

      // ---- f (row-duplicated), scheduled under the swizzle ----
      v2f Ps1[8]; GATHER16(Ps1, s1);
      const float fv = tanh_pre(dot16(FWp, Ps1, fbv));

      y_own = y_own + (fv + (eo + eoth));
      t += 1.0f;
    }
    // write prefetched dx rows into the other buffer
    {
      float* w = xbuf + ((c + 1) & 1) * 1024 + hf2 * 512 + 16 * q;
      float4 d0, d1;
      d0.x = pb0.x - pa0.x; d0.y = pb0.y - pa0.y; d0.z = pb0.z - pa0.z; d0.w = pb0.w - pa0.w;
      d1.x = pb1.x - pa1.x; d1.y = pb1.y - pa1.y; d1.z = pb1.z - pa1.z; d1.w = pb1.w - pa1.w;
      *(float4*)(w)     = d0;  *(float4*)(w + 4)  = d1;
      d0.x = pc0.x - pb0.x; d0.y = pc0.y - pb0.y; d0.z = pc0.z - pb0.z; d0.w = pc0.w - pb0.w;
      d1.x = pc1.x - pb1.x; d1.y = pc1.y - pb1.y; d1.z = pc1.z - pb1.z; d1.w = pc1.w - pb1.w;
      *(float4*)(w + 8) = d0;  *(float4*)(w + 12) = d1;
    }
  }

  // ---- readout t1 ----
  ybq[hf2 * 16 + j] = y_own;
  if (q == 0) {
    float o = rb[0];
#pragma unroll
    for (int k = 0; k < 16; ++k) o = fmaf(rW[k], ybq[hf2 * 16 + k], o);
    out[2 * ch + 1] = o;
  }
}

extern "C" void kernel_launch(void* const* d_in, const int* in_sizes, int n_in,
                              void* d_out, int out_size, void* d_ws, size_t ws_size,
                              hipStream_t stream) {
  (void)in_sizes; (void)n_in; (void)out_size; (void)d_ws; (void)ws_size;
  const float* ts  = (const float*)d_in[0];
  const float* ys  = (const float*)d_in[1];
  const float* iW1 = (const float*)d_in[2];
  const float* ib1 = (const float*)d_in[3];
  const float* iW2 = (const float*)d_in[4];
  const float* ib2 = (const float*)d_in[5];
  const float* vW1 = (const float*)d_in[6];
  const float* vb1 = (const float*)d_in[7];
  const float* vW2 = (const float*)d_in[8];
  const float* vb2 = (const float*)d_in[9];
  const float* cW1 = (const float*)d_in[10];
  const float* cb1 = (const float*)d_in[11];
  const float* cW2 = (const float*)d_in[12];
  const float* cb2 = (const float*)d_in[13];
  const float* rW  = (const float*)d_in[14];
  const float* rb  = (const float*)d_in[15];
  float* out = (float*)d_out;
  hipLaunchKernelGGL(disc_kernel, dim3(256), dim3(64), 0, stream,
                     ts, ys, iW1, ib1, iW2, ib2, vW1, vb1, vW2, vb2,
                     cW1, cb1, cW2, cb2, rW, rb, out);
}

// Round 7
// 1401.130 us; speedup vs baseline: 1.5649x; 1.1494x over previous
//
#include <hip/hip_runtime.h>

#define T_LEN 4096

typedef float v2f __attribute__((ext_vector_type(2)));

__device__ __forceinline__ float frcp(float x)  { return __builtin_amdgcn_rcpf(x); }
__device__ __forceinline__ float fexp2(float x) { return __builtin_amdgcn_exp2f(x); }

template <int CTRL>
__device__ __forceinline__ float mdpp(float x) {
  return __int_as_float(__builtin_amdgcn_mov_dpp(__float_as_int(x), CTRL, 0xF, 0xF, true));
}
template <int CTRL>
__device__ __forceinline__ float dpp_add(float x) {  // x + dpp(x)
  return x + mdpp<CTRL>(x);
}
__device__ __forceinline__ float bperm(int idx_bytes, float x) {
  return __int_as_float(__builtin_amdgcn_ds_bpermute(idx_bytes, __float_as_int(x)));
}
__device__ __forceinline__ void pk_fma(v2f& acc, v2f w, v2f s) {
  asm("v_pk_fma_f32 %0, %1, %2, %0" : "+v"(acc) : "v"(w), "v"(s));
}
// tanh(a) where X = 2*log2e*a  (robust at +-inf)
__device__ __forceinline__ float tanh_pre(float X) {
  return fmaf(-2.0f, frcp(1.0f + fexp2(X)), 1.0f);
}

// Row-gather (within 16-lane rows): P[m] = ( v[(j-m)&15], v[(j-m+8)&15] )
// via row_ror:m / row_ror:m+8. 15 independent DPP movs, depth 1.
#define GATHER16(P, own)                                              \
  P[0].x = (own);            P[0].y = mdpp<0x128>(own);               \
  P[1].x = mdpp<0x121>(own); P[1].y = mdpp<0x129>(own);               \
  P[2].x = mdpp<0x122>(own); P[2].y = mdpp<0x12A>(own);               \
  P[3].x = mdpp<0x123>(own); P[3].y = mdpp<0x12B>(own);               \
  P[4].x = mdpp<0x124>(own); P[4].y = mdpp<0x12C>(own);               \
  P[5].x = mdpp<0x125>(own); P[5].y = mdpp<0x12D>(own);               \
  P[6].x = mdpp<0x126>(own); P[6].y = mdpp<0x12E>(own);               \
  P[7].x = mdpp<0x127>(own); P[7].y = mdpp<0x12F>(own);

__device__ __forceinline__ float dot16(const v2f* __restrict__ W,
                                       const v2f* __restrict__ P, float seed) {
  v2f a0; a0.x = seed; a0.y = 0.0f;
  v2f a1; a1.x = 0.0f; a1.y = 0.0f;
  pk_fma(a0, W[0], P[0]); pk_fma(a1, W[1], P[1]);
  pk_fma(a0, W[2], P[2]); pk_fma(a1, W[3], P[3]);
  pk_fma(a0, W[4], P[4]); pk_fma(a1, W[5], P[5]);
  pk_fma(a0, W[6], P[6]); pk_fma(a1, W[7], P[7]);
  const v2f s = a0 + a1;
  return s.x + s.y;
}

// ONE chain per wave (512 waves), 64 lanes: j = l&15, u = l>>4 (row).
//  y[j], s1[j], s2[j], f[j] row-duplicated x4 (gathers stay in-row DPP).
//  g: lane owns rows h*8 + 2*(j&3) + {0,1}, h = (j&12)+u  -> all 128 rows,
//     2/lane; einsum d-reduce = quad_perm VALU reduce (quad shares h).
//  e[h] -> e[j] redistribution: ONE ds_bpermute (src lane 16*(j&3)+(j&12)+u),
//  its latency covered by the f-dot + f-tanh scheduled after it.
__global__ __launch_bounds__(64, 1) void disc_kernel(
    const float* __restrict__ ts, const float* __restrict__ ys,
    const float* __restrict__ iW1, const float* __restrict__ ib1,
    const float* __restrict__ iW2, const float* __restrict__ ib2,
    const float* __restrict__ vW1, const float* __restrict__ vb1,
    const float* __restrict__ vW2, const float* __restrict__ vb2,
    const float* __restrict__ cW1, const float* __restrict__ cb1,
    const float* __restrict__ cW2, const float* __restrict__ cb2,
    const float* __restrict__ rW, const float* __restrict__ rb,
    float* __restrict__ out)
{
  const int blk = blockIdx.x;
  const int l   = threadIdx.x;
  const int j   = l & 15;
  const int u   = l >> 4;
  const int qd  = j & 3;
  const int h   = (j & 12) + u;

  __shared__ float sbuf[16];
  __shared__ float ybq[16];
  __shared__ __align__(16) float xbuf[1024];  // 2 bufs x 64 steps x 8

  const float* __restrict__ ysc = ys + (size_t)blk * (T_LEN * 8);

  const float NL2E = -1.4426950408889634f;                 // -log2(e)
  const float TSW  = 2.0f * 1.4426950408889634f * 0.909f;  // L2 weight scale
  const float TSB  = 2.0f * 1.4426950408889634f;           // L2 bias scale
  const float NLN2 = -0.6931471805599453f;                 // -ln 2

  // slot->column maps for row_ror gathers
  int idxm[8], idx8[8];
#pragma unroll
  for (int m = 0; m < 8; ++m) { idxm[m] = (j - m) & 15; idx8[m] = (idxm[m] + 8) & 15; }

  // ---- L1 weights: rows j of vW1/cW1 (row-dup), slot-permuted ----
  v2f WVp[8], WCp[8];
#pragma unroll
  for (int m = 0; m < 8; ++m) {
    WVp[m].x = NL2E * vW1[j * 17 + 1 + idxm[m]];
    WVp[m].y = NL2E * vW1[j * 17 + 1 + idx8[m]];
    WCp[m].x = NL2E * cW1[j * 17 + 1 + idxm[m]];
    WCp[m].y = NL2E * cW1[j * 17 + 1 + idx8[m]];
  }
  const float wv_t = NL2E * vW1[j * 17];
  const float bv   = NL2E * vb1[j];
  const float wc_t = NL2E * cW1[j * 17];
  const float bc   = NL2E * cb1[j];

  // ---- L2 f: row j of vW2 (row-dup), slot-permuted ----
  v2f FWp[8];
#pragma unroll
  for (int m = 0; m < 8; ++m) {
    FWp[m].x = TSW * vW2[j * 16 + idxm[m]];
    FWp[m].y = TSW * vW2[j * 16 + idx8[m]];
  }
  const float fbv = TSB * vb2[j];

  // ---- L2 g: rows h*8 + 2*qd + {0,1} of cW2, slot-permuted ----
  v2f GW[2][8];
  float gb[2];
#pragma unroll
  for (int i = 0; i < 2; ++i) {
    const int r = h * 8 + 2 * qd + i;
#pragma unroll
    for (int m = 0; m < 8; ++m) {
      GW[i][m].x = TSW * cW2[r * 16 + idxm[m]];
      GW[i][m].y = TSW * cW2[r * 16 + idx8[m]];
    }
    gb[i] = TSB * cb2[r];
  }

  // bpermute byte-index: src lane holds e[j] after quad-reduce
  const int bpidx = (16 * qd + (j & 12) + u) << 2;

  const float t0 = ts[0];

  // ---- init y0 = iMLP([t0, x0]) (cold; same-wave LDS is ordered) ----
  float y_own;
  {
    float hid = ib1[j] + iW1[j * 9] * t0;
#pragma unroll
    for (int d = 0; d < 8; ++d) hid = fmaf(iW1[j * 9 + 1 + d], ysc[d], hid);
    sbuf[j] = fmaxf(hid, 0.0f);              // rows dup-write identical values
    float y0 = ib2[j];
#pragma unroll
    for (int k = 0; k < 16; ++k) y0 = fmaf(iW2[j * 16 + k], sbuf[k], y0);
    y_own = y0;
  }
  // readout t0
  ybq[j] = y_own;
  if (l == 0) {
    float o = rb[0];
#pragma unroll
    for (int k = 0; k < 16; ++k) o = fmaf(rW[k], ybq[k], o);
    out[2 * blk] = o;
  }

  // ---- dx staging: lane l stages dx row l of chunk 0 ----
  {
    const int r0 = min(l, T_LEN - 1), r1 = min(l + 1, T_LEN - 1);
    const float4 a0 = *(const float4*)(ysc + r0 * 8);
    const float4 a1 = *(const float4*)(ysc + r0 * 8 + 4);
    const float4 b0 = *(const float4*)(ysc + r1 * 8);
    const float4 b1 = *(const float4*)(ysc + r1 * 8 + 4);
    float4 d0, d1;
    d0.x = b0.x - a0.x; d0.y = b0.y - a0.y; d0.z = b0.z - a0.z; d0.w = b0.w - a0.w;
    d1.x = b1.x - a1.x; d1.y = b1.y - a1.y; d1.z = b1.z - a1.z; d1.w = b1.w - a1.w;
    *(float4*)(xbuf + l * 8)     = d0;
    *(float4*)(xbuf + l * 8 + 4) = d1;
  }

  float t = t0;
  for (int c = 0; c < 64; ++c) {
    // prefetch next chunk's rows into registers (clamped)
    float4 pa0, pa1, pb0, pb1;
    {
      const int base = (c + 1 < 64 ? (c + 1) * 64 : c * 64);
      const int r0 = min(base + l, T_LEN - 1), r1 = min(base + l + 1, T_LEN - 1);
      pa0 = *(const float4*)(ysc + r0 * 8);
      pa1 = *(const float4*)(ysc + r0 * 8 + 4);
      pb0 = *(const float4*)(ysc + r1 * 8);
      pb1 = *(const float4*)(ysc + r1 * 8 + 4);
    }
    const float* __restrict__ xb = xbuf + (c & 1) * 512;
    const int nsteps = min(64, (T_LEN - 1) - c * 64);
    for (int js = 0; js < nsteps; ++js) {
      // this lane's 2 dx components (d = 2qd, 2qd+1); read early, used late
      const float2 dx2 = *(const float2*)(xb + js * 8 + 2 * qd);

      // ---- y gather + L1 (s1,s2 on every lane; rows duplicate) ----
      v2f Py[8]; GATHER16(Py, y_own);
      const float u1 = dot16(WVp, Py, fmaf(wv_t, t, bv));
      const float u2 = dot16(WCp, Py, fmaf(wc_t, t, bc));
      const float s1 = (u1 * NLN2) * frcp(1.0f + fexp2(u1));
      const float s2 = (u2 * NLN2) * frcp(1.0f + fexp2(u2));

      // ---- g: 2 in-lane dots on gathered s2, tanh, einsum partial ----
      v2f Ps2[8]; GATHER16(Ps2, s2);
      const float tg0 = tanh_pre(dot16(GW[0], Ps2, gb[0]));
      const float tg1 = tanh_pre(dot16(GW[1], Ps2, gb[1]));
      float pr = fmaf(tg0, dx2.x, tg1 * dx2.y);
      // quad reduce over d-pairs (VALU): all quad lanes get e[h]
      pr = dpp_add<0xB1>(pr);
      pr = dpp_add<0x4E>(pr);
      // redistribute e[h] -> e[j] (the ONE DS op); f fills its latency
      const float ej = bperm(bpidx, pr);

      // ---- f (row-duplicated), scheduled under the bpermute ----
      v2f Ps1[8]; GATHER16(Ps1, s1);
      const float fv = tanh_pre(dot16(FWp, Ps1, fbv));

      y_own = y_own + (fv + ej);
      t += 1.0f;
    }
    // write prefetched dx rows into the other buffer
    {
      float* w = xbuf + ((c + 1) & 1) * 512 + l * 8;
      float4 d0, d1;
      d0.x = pb0.x - pa0.x; d0.y = pb0.y - pa0.y; d0.z = pb0.z - pa0.z; d0.w = pb0.w - pa0.w;
      d1.x = pb1.x - pa1.x; d1.y = pb1.y - pa1.y; d1.z = pb1.z - pa1.z; d1.w = pb1.w - pa1.w;
      *(float4*)(w)     = d0;
      *(float4*)(w + 4) = d1;
    }
  }

  // ---- readout t1 ----
  ybq[j] = y_own;
  if (l == 0) {
    float o = rb[0];
#pragma unroll
    for (int k = 0; k < 16; ++k) o = fmaf(rW[k], ybq[k], o);
    out[2 * blk + 1] = o;
  }
}

extern "C" void kernel_launch(void* const* d_in, const int* in_sizes, int n_in,
                              void* d_out, int out_size, void* d_ws, size_t ws_size,
                              hipStream_t stream) {
  (void)in_sizes; (void)n_in; (void)out_size; (void)d_ws; (void)ws_size;
  const float* ts  = (const float*)d_in[0];
  const float* ys  = (const float*)d_in[1];
  const float* iW1 = (const float*)d_in[2];
  const float* ib1 = (const float*)d_in[3];
  const float* iW2 = (const float*)d_in[4];
  const float* ib2 = (const float*)d_in[5];
  const float* vW1 = (const float*)d_in[6];
  const float* vb1 = (const float*)d_in[7];
  const float* vW2 = (const float*)d_in[8];
  const float* vb2 = (const float*)d_in[9];
  const float* cW1 = (const float*)d_in[10];
  const float* cb1 = (const float*)d_in[11];
  const float* cW2 = (const float*)d_in[12];
  const float* cb2 = (const float*)d_in[13];
  const float* rW  = (const float*)d_in[14];
  const float* rb  = (const float*)d_in[15];
  float* out = (float*)d_out;
  hipLaunchKernelGGL(disc_kernel, dim3(512), dim3(64), 0, stream,
                     ts, ys, iW1, ib1, iW2, ib2, vW1, vb1, vW2, vb2,
                     cW1, cb1, cW2, cb2, rW, rb, out);
}